// Round 1
// baseline (263.390 us; speedup 1.0000x reference)
//
#include <hip/hip_runtime.h>
#include <hip/hip_bf16.h>

typedef __bf16 bf16_t;
typedef __bf16 bf16x8 __attribute__((ext_vector_type(8)));
typedef float f32x4 __attribute__((ext_vector_type(4)));
typedef short short4v __attribute__((ext_vector_type(4)));

#define D_MODEL 1024
#define T_SEQ 2048
#define NH 16
#define DKD 64
#define X_ELEMS (4194304u)   // 2*2048*1024
#define W_ELEMS (1048576u)   // 1024*1024

__device__ __forceinline__ void async16(const bf16_t* g, bf16_t* l) {
    __builtin_amdgcn_global_load_lds((const __attribute__((address_space(1))) void*)g,
                                     (__attribute__((address_space(3))) void*)l, 16, 0, 0);
}

// ---------------- fp32 -> bf16 conversion for x + 4 weights ----------------
__global__ __launch_bounds__(256) void convert_kernel(
    const float* __restrict__ x, const float* __restrict__ wq,
    const float* __restrict__ wk, const float* __restrict__ wv,
    const float* __restrict__ wo,
    bf16_t* __restrict__ xb, bf16_t* __restrict__ wqb, bf16_t* __restrict__ wkb,
    bf16_t* __restrict__ wvb, bf16_t* __restrict__ wob)
{
    size_t idx = ((size_t)blockIdx.x * 256 + threadIdx.x) * 4;
    const float* src; bf16_t* dst; size_t off;
    if (idx < X_ELEMS) { src = x; dst = xb; off = idx; }
    else {
        size_t r = idx - X_ELEMS;
        unsigned w = (unsigned)(r >> 20);
        off = r & (W_ELEMS - 1);
        src = (w == 0) ? wq : (w == 1) ? wk : (w == 2) ? wv : wo;
        dst = (w == 0) ? wqb : (w == 1) ? wkb : (w == 2) ? wvb : wob;
    }
    float4 v = *(const float4*)(src + off);
    union { bf16_t b[4]; short4v s; } u;
    u.b[0] = (bf16_t)v.x; u.b[1] = (bf16_t)v.y;
    u.b[2] = (bf16_t)v.z; u.b[3] = (bf16_t)v.w;
    *(short4v*)(dst + off) = u.s;
}

// ---------------- RoPE cos/sin tables: [T][32] ----------------
__global__ __launch_bounds__(256) void rope_kernel(float* __restrict__ cost, float* __restrict__ sint)
{
    int idx = blockIdx.x * 256 + threadIdx.x;  // < 2048*32
    int t = idx >> 5, i = idx & 31;
    // inv_freq = 10000^(-i/32);  log(10000)/32 = 0.28782313662425572
    float inv = expf(-0.28782313662425572f * (float)i);
    float ang = (float)t * inv;
    float s, c;
    sincosf(ang, &s, &c);
    cost[idx] = c; sint[idx] = s;
}

// ---------------- GEMM C[m,n] = sum_k A[m,k]*W[n,k]  (m97 structure) ----------------
// mode 0: Q out (rope, (B,H,T,DK) bf16)   mode 1: K out (rope, (B,H,T,DK) bf16)
// mode 2: V out (transposed (B,H,DK,T) bf16)   mode 3: plain fp32 out [M,N]
__global__ __launch_bounds__(256) void gemm_fused(
    const bf16_t* __restrict__ A,
    const bf16_t* __restrict__ W0, const bf16_t* __restrict__ W1, const bf16_t* __restrict__ W2,
    bf16_t* __restrict__ qout, bf16_t* __restrict__ kout, bf16_t* __restrict__ vout,
    const float* __restrict__ cost, const float* __restrict__ sint,
    float* __restrict__ fout, int modeBase)
{
    const int K = 1024;
    __shared__ bf16_t As[128 * 32];
    __shared__ bf16_t Bs[128 * 32];
    const int tid = threadIdx.x;
    const int wave = tid >> 6, lane = tid & 63;
    const int quad = lane >> 4, l16 = lane & 15;
    const int m0 = blockIdx.x * 128;
    const int n0 = blockIdx.y * 128;
    const int wm = (wave >> 1) * 64, wn = (wave & 1) * 64;
    const int mode = modeBase + blockIdx.z;
    const bf16_t* W = (mode == 1) ? W1 : (mode == 2) ? W2 : W0;

    const f32x4 fzero = {0.f, 0.f, 0.f, 0.f};
    f32x4 acc[4][4];
    #pragma unroll
    for (int i = 0; i < 4; ++i)
        #pragma unroll
        for (int j = 0; j < 4; ++j) acc[i][j] = fzero;

    for (int k0 = 0; k0 < K; k0 += 32) {
        __syncthreads();
        #pragma unroll
        for (int c = 0; c < 2; ++c) {
            int G = c * 256 + tid;
            int row = G >> 2, go = G & 3;           // 4 granules (8 bf16) per 32-elem row
            async16(A + (size_t)(m0 + row) * K + (k0 + go * 8), As + (size_t)(c * 256 + wave * 64) * 8);
            async16(W + (size_t)(n0 + row) * K + (k0 + go * 8), Bs + (size_t)(c * 256 + wave * 64) * 8);
        }
        __syncthreads();
        bf16x8 af[4], bfv[4];
        #pragma unroll
        for (int mi = 0; mi < 4; ++mi)
            af[mi] = *(const bf16x8*)(As + (wm + mi * 16 + l16) * 32 + quad * 8);
        #pragma unroll
        for (int ni = 0; ni < 4; ++ni)
            bfv[ni] = *(const bf16x8*)(Bs + (wn + ni * 16 + l16) * 32 + quad * 8);
        #pragma unroll
        for (int mi = 0; mi < 4; ++mi)
            #pragma unroll
            for (int ni = 0; ni < 4; ++ni)
                acc[mi][ni] = __builtin_amdgcn_mfma_f32_16x16x32_bf16(af[mi], bfv[ni], acc[mi][ni], 0, 0, 0);
    }

    // epilogue: C/D layout col=lane&15, row=quad*4+reg
    #pragma unroll
    for (int mi = 0; mi < 4; ++mi) {
        #pragma unroll
        for (int ni = 0; ni < 4; ++ni) {
            #pragma unroll
            for (int reg = 0; reg < 4; ++reg) {
                int row = m0 + wm + mi * 16 + quad * 4 + reg;
                int col = n0 + wn + ni * 16 + l16;
                float v = acc[mi][ni][reg];
                if (mode == 3) {
                    fout[(size_t)row * D_MODEL + col] = v;
                } else {
                    int t = row & (T_SEQ - 1), b = row >> 11;
                    int h = col >> 6, dk = col & 63;
                    if (mode == 2) {
                        vout[(((size_t)b * NH + h) * DKD + dk) * T_SEQ + t] = (bf16_t)v;
                    } else {
                        float vp = __shfl_xor(v, 1);
                        int fi = dk >> 1;
                        float c = cost[t * 32 + fi], s = sint[t * 32 + fi];
                        float r = (dk & 1) ? (vp * s + v * c) : (v * c - vp * s);
                        bf16_t* dst = (mode == 0) ? qout : kout;
                        dst[(((size_t)b * NH + h) * T_SEQ + t) * DKD + dk] = (bf16_t)r;
                    }
                }
            }
        }
    }
}

// ---------------- flash attention (causal, online softmax) ----------------
// grid: (T/64, B*H). block 256 = 4 waves; wave w owns q rows [q0+16w, q0+16w+16)
__global__ __launch_bounds__(256) void attn_kernel(
    const bf16_t* __restrict__ Q, const bf16_t* __restrict__ Kb,
    const bf16_t* __restrict__ Vt, bf16_t* __restrict__ O)
{
    __shared__ bf16_t Ks[64 * 64];
    __shared__ bf16_t Vs[64 * 64];
    __shared__ bf16_t Pw[4][16 * 72];   // per-wave P buffer, padded rows (72) -> conflict-free A-frag reads
    const int tid = threadIdx.x;
    const int wave = tid >> 6, lane = tid & 63;
    const int quad = lane >> 4, l16 = lane & 15;
    const int qt = blockIdx.x;
    const int bh = blockIdx.y;
    const int q0 = qt * 64;

    // Q A-frags: m = lane&15, k(d) = quad*8+j (+32 for second frag)
    bf16x8 qf[2];
    {
        const bf16_t* qbase = Q + ((size_t)bh * T_SEQ + q0 + wave * 16 + l16) * DKD;
        qf[0] = *(const bf16x8*)(qbase + quad * 8);
        qf[1] = *(const bf16x8*)(qbase + 32 + quad * 8);
    }
    const f32x4 fzero = {0.f, 0.f, 0.f, 0.f};
    f32x4 oacc[4];
    #pragma unroll
    for (int i = 0; i < 4; ++i) oacc[i] = fzero;
    float mst[4], lst[4];
    #pragma unroll
    for (int r = 0; r < 4; ++r) { mst[r] = -__builtin_inff(); lst[r] = 0.f; }

    for (int kt = 0; kt <= qt; ++kt) {
        const int k0 = kt * 64;
        __syncthreads();
        // stage K (t-major) and V^T (d-major) tiles, 16B-granule XOR swizzle: pos p stores granule p^(row&7)
        #pragma unroll
        for (int c = 0; c < 2; ++c) {
            int G = c * 256 + tid;
            int row = G >> 3, p = G & 7;
            int go = p ^ (row & 7);
            async16(Kb + ((size_t)bh * T_SEQ + k0 + row) * DKD + go * 8, Ks + (size_t)(c * 256 + wave * 64) * 8);
            async16(Vt + ((size_t)bh * DKD + row) * T_SEQ + k0 + go * 8, Vs + (size_t)(c * 256 + wave * 64) * 8);
        }
        __syncthreads();

        // S = Q K^T : 4 key-tiles of 16, 2 k-steps over d
        f32x4 sfr[4];
        #pragma unroll
        for (int ni = 0; ni < 4; ++ni) {
            f32x4 z = fzero;
            #pragma unroll
            for (int ks = 0; ks < 2; ++ks) {
                int r = ni * 16 + l16;
                int p = (ks * 4 + quad) ^ (r & 7);
                bf16x8 kf = *(const bf16x8*)(Ks + r * 64 + p * 8);
                z = __builtin_amdgcn_mfma_f32_16x16x32_bf16(qf[ks], kf, z, 0, 0, 0);
            }
            sfr[ni] = z;
        }
        // online softmax, rows = quad*4+reg, cols = ni*16+l16
        float alpha[4];
        #pragma unroll
        for (int reg = 0; reg < 4; ++reg) {
            int qpos = q0 + wave * 16 + quad * 4 + reg;
            float mx = -__builtin_inff();
            #pragma unroll
            for (int ni = 0; ni < 4; ++ni) {
                float v = sfr[ni][reg] * 0.125f;
                int kpos = k0 + ni * 16 + l16;
                v = (kpos > qpos) ? -__builtin_inff() : v;
                sfr[ni][reg] = v;
                mx = fmaxf(mx, v);
            }
            #pragma unroll
            for (int off = 1; off < 16; off <<= 1) mx = fmaxf(mx, __shfl_xor(mx, off));
            float mnew = fmaxf(mst[reg], mx);
            alpha[reg] = __expf(mst[reg] - mnew);
            mst[reg] = mnew;
            float sm = 0.f;
            #pragma unroll
            for (int ni = 0; ni < 4; ++ni) {
                float p = __expf(sfr[ni][reg] - mnew);
                sfr[ni][reg] = p;
                sm += p;
            }
            #pragma unroll
            for (int off = 1; off < 16; off <<= 1) sm += __shfl_xor(sm, off);
            lst[reg] = lst[reg] * alpha[reg] + sm;
        }
        #pragma unroll
        for (int di = 0; di < 4; ++di)
            #pragma unroll
            for (int reg = 0; reg < 4; ++reg) oacc[di][reg] *= alpha[reg];

        // P: C/D layout -> LDS -> A-operand layout (wave-private, no barrier needed)
        bf16_t* pw = &Pw[wave][0];
        #pragma unroll
        for (int ni = 0; ni < 4; ++ni)
            #pragma unroll
            for (int reg = 0; reg < 4; ++reg)
                pw[(quad * 4 + reg) * 72 + ni * 16 + l16] = (bf16_t)sfr[ni][reg];
        bf16x8 pf[2];
        #pragma unroll
        for (int h2 = 0; h2 < 2; ++h2)
            pf[h2] = *(const bf16x8*)(pw + l16 * 72 + h2 * 32 + quad * 8);

        // O += P V : 4 d-tiles, 2 k-steps over keys
        #pragma unroll
        for (int di = 0; di < 4; ++di) {
            #pragma unroll
            for (int h2 = 0; h2 < 2; ++h2) {
                int r = di * 16 + l16;
                int p = (h2 * 4 + quad) ^ (r & 7);
                bf16x8 vf = *(const bf16x8*)(Vs + r * 64 + p * 8);
                oacc[di] = __builtin_amdgcn_mfma_f32_16x16x32_bf16(pf[h2], vf, oacc[di], 0, 0, 0);
            }
        }
    }

    // epilogue -> (B,T,D_MODEL) bf16
    const int b = bh >> 4, h = bh & 15;
    #pragma unroll
    for (int di = 0; di < 4; ++di) {
        #pragma unroll
        for (int reg = 0; reg < 4; ++reg) {
            int qpos = q0 + wave * 16 + quad * 4 + reg;
            float v = oacc[di][reg] / lst[reg];
            O[((size_t)b * T_SEQ + qpos) * D_MODEL + h * DKD + di * 16 + l16] = (bf16_t)v;
        }
    }
}

extern "C" void kernel_launch(void* const* d_in, const int* in_sizes, int n_in,
                              void* d_out, int out_size, void* d_ws, size_t ws_size,
                              hipStream_t stream)
{
    const float* x  = (const float*)d_in[0];
    const float* wq = (const float*)d_in[1];
    const float* wk = (const float*)d_in[2];
    const float* wv = (const float*)d_in[3];
    const float* wo = (const float*)d_in[4];
    float* out = (float*)d_out;

    char* ws = (char*)d_ws;
    size_t off = 0;
    auto alloc = [&](size_t bytes) -> void* {
        void* p = ws + off; off += (bytes + 255) & ~(size_t)255; return p;
    };
    bf16_t* xb   = (bf16_t*)alloc((size_t)X_ELEMS * 2);
    bf16_t* wqb  = (bf16_t*)alloc((size_t)W_ELEMS * 2);
    bf16_t* wkb  = (bf16_t*)alloc((size_t)W_ELEMS * 2);
    bf16_t* wvb  = (bf16_t*)alloc((size_t)W_ELEMS * 2);
    bf16_t* wob  = (bf16_t*)alloc((size_t)W_ELEMS * 2);
    bf16_t* qb   = (bf16_t*)alloc((size_t)X_ELEMS * 2);
    bf16_t* kb   = (bf16_t*)alloc((size_t)X_ELEMS * 2);
    bf16_t* vtb  = (bf16_t*)alloc((size_t)X_ELEMS * 2);
    bf16_t* ob   = (bf16_t*)alloc((size_t)X_ELEMS * 2);
    float*  cost = (float*)alloc((size_t)T_SEQ * 32 * 4);
    float*  sint = (float*)alloc((size_t)T_SEQ * 32 * 4);

    convert_kernel<<<8192, 256, 0, stream>>>(x, wq, wk, wv, wo, xb, wqb, wkb, wvb, wob);
    rope_kernel<<<256, 256, 0, stream>>>(cost, sint);
    // Q, K, V projections (+RoPE, +V transpose) in one z=3 launch
    gemm_fused<<<dim3(32, 8, 3), 256, 0, stream>>>(xb, wqb, wkb, wvb, qb, kb, vtb, cost, sint, nullptr, 0);
    attn_kernel<<<dim3(32, 32), 256, 0, stream>>>(qb, kb, vtb, ob);
    // output projection -> fp32
    gemm_fused<<<dim3(32, 8, 1), 256, 0, stream>>>(ob, wob, nullptr, nullptr, nullptr, nullptr, nullptr,
                                                   cost, sint, out, 3);
}